// Round 13
// baseline (811.797 us; speedup 1.0000x reference)
//
#include <hip/hip_runtime.h>
#include <math.h>

#define NB 64      // batch
#define TTX 256    // text timesteps
#define TTP 16     // topic timesteps
#define EE 300     // embedding dim
#define HH 512     // hidden
#define SENT16 0x7FC1u        // bf16 NaN-payload sentinel (real h never NaN)
#define SENT32 0x7FC17FC1u

typedef __attribute__((ext_vector_type(4))) float f32x4;
typedef __attribute__((ext_vector_type(8))) short short8;

__device__ __forceinline__ unsigned short bf16cvt(float f) {
  unsigned u = __float_as_uint(f);
  u += 0x7FFFu + ((u >> 16) & 1u);   // RNE
  return (unsigned short)(u >> 16);
}

// ---------------------------------------------------------------------------
// prep: (a) poison the bf16 h-ring (every call: graph-replay deterministic),
// (b) build Wxf: per-(phase,slice) fragment-ordered bf16 x-part weights so
//     recur's per-step xp B-loads are contiguous 16B/lane L1-resident reads.
//     Wxf[((((ph*16+slice)*4+ns)*10+kc)*64+lane)*8+e] = W[k][col], where
//     k = kc*32 + 8*(lane>>4) + e (0-pad k>=300), gate = ns>>1 (0=z,1=o),
//     col = slice*32 + (ns&1)*16 + (lane&15). ph0 = text W, ph1 = topic W.
// ---------------------------------------------------------------------------
__global__ __launch_bounds__(256) void sd_prep(
    const float* __restrict__ tWz, const float* __restrict__ tWo,
    const float* __restrict__ pWz, const float* __restrict__ pWo,
    unsigned short* __restrict__ wxf, unsigned* __restrict__ ring32)
{
  const int i = blockIdx.x * 256 + threadIdx.x;   // [0, 655360)
  if (i < 65536) ring32[i] = SENT32;              // whole 4-slot ring (u32)
  const int ph = i / 327680;
  const int r  = i - ph * 327680;
  const int slice = r / 20480;
  const int r2 = r - slice * 20480;
  const int ns = r2 / 5120;
  const int r3 = r2 - ns * 5120;
  const int kc = r3 / 512;
  const int r4 = r3 - kc * 512;
  const int lane = r4 >> 3;
  const int e    = r4 & 7;
  const int k = kc * 32 + 8 * (lane >> 4) + e;
  const int col = slice * 32 + (ns & 1) * 16 + (lane & 15);
  const float* W = ph ? ((ns >> 1) ? pWo : pWz) : ((ns >> 1) ? tWo : tWz);
  const float v = (k < 300) ? W[(size_t)k * HH + col] : 0.f;
  wxf[i] = bf16cvt(v);
}

// ---------------------------------------------------------------------------
// Persistent recurrence — EXACT r10 skeleton (256 blocks, serial phases,
// block-wide sentinel poll, 2 syncs/step, vmcnt(1), bf16 ring — 430us
// verified) with the xproj GEMM fused in:
//   * per step, each block computes its OWN 4-row x 64-col xp slice:
//     - emb rows of the step's 4 tokens gathered+cvt to LDS BEFORE the poll
//       (loads issue early; latency absorbed by the poll spin)
//     - 5 MFMAs/wave between the syncs: wave wv does ns=wv&3 (col subtile),
//       k-half wv>>2 (kc 5..9 or 0..4); partials to red2; writer tail sums
//       the two k-halves + bias.
//   * the xproj kernel, the xp buffers (71MB writes + 17MB reads) and their
//     launch gap are deleted. Exchange protocol untouched (r4/r9/r10 proofs).
// ---------------------------------------------------------------------------
__global__ __launch_bounds__(512) void sd_recur(
    const int* __restrict__ text_idx, const int* __restrict__ topic_idx,
    const float* __restrict__ emb,
    const float* __restrict__ tWz, const float* __restrict__ tWo,
    const float* __restrict__ pWz, const float* __restrict__ pWo,
    const float* __restrict__ tbz, const float* __restrict__ tbo,
    const float* __restrict__ pbz, const float* __restrict__ pbo,
    const unsigned short* __restrict__ wxf,
    float* __restrict__ text_out, unsigned short* __restrict__ hring,
    float* __restrict__ topic_h)
{
  __shared__ alignas(16) unsigned short h_bf[2][2080];   // bf16 h, [4 rows][520]
  __shared__ alignas(16) float red[2][2048];             // h-matvec partials
  __shared__ alignas(16) float red2[2][512];             // xp partials [8wv][4r][16]
  __shared__ alignas(16) unsigned short emb_bf[2][1280]; // [4 rows][320]
  __shared__ int tok_lds[1088];                          // [4 rows][272]

  const int tid = threadIdx.x;
  const int bid = blockIdx.x;
  const int x = bid & 7;           // XCD (heuristic placement)
  const int q = bid >> 3;
  const int g = x + 8 * (q >> 4);  // batch group 0..15
  const int slice = q & 15;        // dim slice 0..15
  const int b0 = g * 4;
  const int c_base = slice * 32;

  const int wv = tid >> 6;         // wave id = k-eighth (0..7)
  const int lane = tid & 63;
  const int lg = lane >> 4;        // k-slot group 0..3
  const int l15 = lane & 15;

  const int bi_w = tid >> 5;       // writer mapping (tid<128): batch row 0..3
  const int dw = tid & 31;

  const size_t wslot_off = (size_t)(b0 + bi_w) * HH + c_base + dw;

  // startup: preload this group's token ids (text rows 0..255, topic 256..271)
  for (int i = tid; i < 4 * TTX; i += 512) {
    const int row = i >> 8, t0 = i & 255;
    tok_lds[row * 272 + t0] = text_idx[(b0 + row) * TTX + t0];
  }
  if (tid < 64) {
    const int row = tid >> 4, t0 = tid & 15;
    tok_lds[row * 272 + 256 + t0] = topic_idx[(b0 + row) * TTP + t0];
  }
  __syncthreads();

  int u = 0;  // global step counter across both phases

  for (int ph = 0; ph < 2; ++ph) {
    const float* Wz = ph ? pWz : tWz;
    const float* Wo = ph ? pWo : tWo;
    const int T = ph ? TTP : TTX;
    const int tb = ph ? 256 : 0;
    const unsigned short* wxp = wxf + ph * 327680 + slice * 20480;

    // writer bias registers (x-projection bias, added in the tail)
    float bzr = 0.f, bor = 0.f;
    if (tid < 128) {
      bzr = (ph ? pbz : tbz)[c_base + dw];
      bor = (ph ? pbo : tbo)[c_base + dw];
    }

    float hprev_r = 0.f;  // writer's own h (fp32-exact), reset per phase

    // --- prep W h-part bf16 B-fragments (once per phase) ----------------
    short8 wfrag[4][2];
#pragma unroll
    for (int ns = 0; ns < 4; ++ns) {
      const float* Wg = (ns < 2) ? Wz : Wo;
      const int dim = (ns & 1) * 16 + l15;
#pragma unroll
      for (int kc = 0; kc < 2; ++kc) {
        const int kb = wv * 64 + kc * 32 + 8 * lg;
        short8 f;
#pragma unroll
        for (int e = 0; e < 8; ++e)
          f[e] = (short)bf16cvt(Wg[(size_t)(EE + kb + e) * HH + c_base + dim]);
        wfrag[ns][kc] = f;
      }
    }

    for (int t = 0; t < T; ++t, ++u) {
      const int cur = u & 1;
      const bool do_poll = (u > 0);
      const bool use_h   = (t > 0);

      // emb gather for this step's xp (issue BEFORE the poll: the spin
      // absorbs the load latency). [4 rows][320], 0-pad k>=300.
      for (int i = tid; i < 1280; i += 512) {
        const int row = i / 320;
        const int k = i - row * 320;
        const int tk = tok_lds[row * 272 + tb + t];
        float v = 0.f;
        if (k < 300) v = emb[(size_t)tk * EE + k];
        emb_bf[cur][row * 320 + k] = bf16cvt(v);
      }

      if (do_poll) {
        // block-wide poll-stage: one u64 (4 bf16) per thread (r10-verified)
        const unsigned long long* src64 = (const unsigned long long*)
            (hring + (size_t)(u & 3) * NB * HH + (size_t)b0 * HH);
        unsigned long long v;
        for (;;) {
          v = __hip_atomic_load(src64 + tid, __ATOMIC_RELAXED, __HIP_MEMORY_SCOPE_AGENT);
          const unsigned lo = (unsigned)v, hi = (unsigned)(v >> 32);
          if ((lo & 0xFFFFu) != SENT16 && (lo >> 16) != SENT16 &&
              (hi & 0xFFFFu) != SENT16 && (hi >> 16) != SENT16) break;
          __builtin_amdgcn_s_sleep(1);
        }
        *(unsigned long long*)&h_bf[cur][(tid >> 7) * 520 + (tid & 127) * 4] = v;
      }

      __syncthreads();  // sync1: poll + emb stage visible

      // Safe to recycle slot (u-1)&3 now (poll success => consumers done).
      if (do_poll && tid < 128 && !(tid & 1))
        __hip_atomic_store((unsigned*)(hring + (size_t)((u - 1) & 3) * NB * HH + wslot_off),
                           SENT32, __ATOMIC_RELAXED, __HIP_MEMORY_SCOPE_AGENT);

      if (use_h) {
        const unsigned short* hb = &h_bf[cur][(lane & 3) * 520 + wv * 64 + 8 * lg];
        const short8 a0 = *reinterpret_cast<const short8*>(hb + 0);
        const short8 a1 = *reinterpret_cast<const short8*>(hb + 32);

        f32x4 acc[4];
#pragma unroll
        for (int ns = 0; ns < 4; ++ns) {
          acc[ns] = (f32x4){0.f, 0.f, 0.f, 0.f};
          acc[ns] = __builtin_amdgcn_mfma_f32_16x16x32_bf16(a0, wfrag[ns][0], acc[ns], 0, 0, 0);
          acc[ns] = __builtin_amdgcn_mfma_f32_16x16x32_bf16(a1, wfrag[ns][1], acc[ns], 0, 0, 0);
        }
        if (lane < 16) {
#pragma unroll
          for (int ns = 0; ns < 4; ++ns)
#pragma unroll
            for (int r = 0; r < 4; ++r)
              red[cur][wv * 256 + r * 64 + ns * 16 + lane] = acc[ns][r];
        }
      }

      // xp slice matvec (every step): wave wv -> ns=wv&3, k-half wv>>2
      {
        const int ns = wv & 3;
        const int kh = wv >> 2;
        const unsigned short* wxb = wxp + ns * 5120 + (kh * 5) * 512 + lane * 8;
        const unsigned short* ea  = &emb_bf[cur][(lane & 3) * 320 + (kh * 5) * 32 + 8 * lg];
        f32x4 accx = (f32x4){0.f, 0.f, 0.f, 0.f};
#pragma unroll
        for (int k5 = 0; k5 < 5; ++k5) {
          const short8 ax = *reinterpret_cast<const short8*>(ea + k5 * 32);
          const short8 bx = *reinterpret_cast<const short8*>(wxb + k5 * 512);
          accx = __builtin_amdgcn_mfma_f32_16x16x32_bf16(ax, bx, accx, 0, 0, 0);
        }
        if (lane < 16) {
#pragma unroll
          for (int r = 0; r < 4; ++r)
            red2[cur][wv * 64 + r * 16 + lane] = accx[r];
        }
      }

      __syncthreads();  // sync2: partials visible

      if (tid < 128) {
        float zp = 0.f, op = 0.f;
        if (use_h) {
#pragma unroll
          for (int k2 = 0; k2 < 8; ++k2) {
            zp += red[cur][k2 * 256 + bi_w * 64 + dw];        // gate z
            op += red[cur][k2 * 256 + bi_w * 64 + 32 + dw];   // gate o
          }
        }
        // xp from red2: ns (z) = dw>>4, ns (o) = 2+(dw>>4); sum both k-halves
        const int nsz = dw >> 4;
        const int cl = bi_w * 16 + (dw & 15);
        const float xpz = red2[cur][nsz * 64 + cl] + red2[cur][(4 + nsz) * 64 + cl] + bzr;
        const float xpo = red2[cur][(2 + nsz) * 64 + cl] + red2[cur][(6 + nsz) * 64 + cl] + bor;

        const float a = zp + xpz;
        const float z = 1.f / (1.f + __expf(-a));
        const float bv = op + xpo;
        const float ab = fabsf(bv);
        const float e2 = __expf(-2.f * ab);
        const float htl = __builtin_copysignf((1.f - e2) / (1.f + e2), bv);
        const float hn = (1.f - z) * hprev_r + z * htl;
        hprev_r = hn;

        // pack 2 bf16 per lane pair; even thread stores one sc1 dword
        const unsigned short hb16 = bf16cvt(hn);
        const unsigned packed = (unsigned)hb16 |
                                ((unsigned)__shfl_down((int)hb16, 1, 64) << 16);

        // drain everything EXCEPT this step's own poison (r9/r10 proof)
        asm volatile("s_waitcnt vmcnt(1)" ::: "memory");
        if (!(tid & 1))
          __hip_atomic_store((unsigned*)(hring + (size_t)((u + 1) & 3) * NB * HH + wslot_off),
                             packed, __ATOMIC_RELAXED, __HIP_MEMORY_SCOPE_AGENT);
        if (ph == 0)
          text_out[((size_t)(b0 + bi_w) * TTX + t) * HH + c_base + dw] = hn;
        else if (t == T - 1)
          topic_h[(size_t)(b0 + bi_w) * HH + c_base + dw] = hn;
      }
      // no trailing barrier: 2-deep buffers tolerate one-phase skew
    }
  }
}

// ---------------------------------------------------------------------------
// attention + FC head fused (unchanged from round 9/10, verified)
// ---------------------------------------------------------------------------
__global__ __launch_bounds__(256) void sd_att_fc(
    const float* __restrict__ text_out, const float* __restrict__ topic_h,
    const float* __restrict__ att_W, const float* __restrict__ att_b,
    const float* __restrict__ fc1_W, const float* __restrict__ fc1_b,
    const float* __restrict__ fc2_W, const float* __restrict__ fc2_b,
    float* __restrict__ logits, float* __restrict__ weights_out)
{
  __shared__ alignas(16) float aw[1024];
  __shared__ alignas(16) float th[512];
  __shared__ float sc_s[256];
  __shared__ float sred[256];
  __shared__ float wsh[256];
  __shared__ alignas(16) float feat[1024];
  __shared__ float hid[512];
  const int b = blockIdx.x, tid = threadIdx.x;

  for (int i = tid; i < 1024; i += 256) aw[i] = att_W[i];
  for (int i = tid; i < 512; i += 256) th[i] = topic_h[(size_t)b * HH + i];
  __syncthreads();

  float part = 0.f;
  for (int i = tid; i < 512; i += 256) part += th[i] * aw[512 + i];
  sred[tid] = part;
  __syncthreads();
  for (int s = 128; s > 0; s >>= 1) { if (tid < s) sred[tid] += sred[tid + s]; __syncthreads(); }
  const float cb = sred[0] + att_b[0];
  __syncthreads();

  const int gr = tid >> 5, ln = tid & 31;
  for (int rep = 0; rep < 32; ++rep) {
    const int t = rep * 8 + gr;
    const float* row = text_out + ((size_t)b * TTX + t) * HH;
    float p = 0.f;
#pragma unroll
    for (int j = 0; j < 4; ++j) {
      const float4 v  = *(const float4*)(row + ln * 4 + 128 * j);
      const float4 w4 = *(const float4*)(aw  + ln * 4 + 128 * j);
      p += v.x * w4.x + v.y * w4.y + v.z * w4.z + v.w * w4.w;
    }
#pragma unroll
    for (int o = 16; o > 0; o >>= 1) p += __shfl_xor(p, o, 32);
    if (ln == 0) sc_s[t] = p + cb;
  }
  __syncthreads();

  const float sc = sc_s[tid];
  sred[tid] = sc; __syncthreads();
  for (int s = 128; s > 0; s >>= 1) { if (tid < s) sred[tid] = fmaxf(sred[tid], sred[tid + s]); __syncthreads(); }
  const float m = sred[0];
  __syncthreads();
  const float e = expf(sc - m);
  sred[tid] = e; __syncthreads();
  for (int s = 128; s > 0; s >>= 1) { if (tid < s) sred[tid] += sred[tid + s]; __syncthreads(); }
  const float wv = e / sred[0];
  wsh[tid] = wv;
  weights_out[(size_t)b * TTX + tid] = wv;
  __syncthreads();

  for (int rep = 0; rep < 2; ++rep) {
    const int dcol = rep * 256 + tid;
    float accc = 0.f;
    const float* base = text_out + (size_t)b * TTX * HH + dcol;
    for (int t2 = 0; t2 < TTX; ++t2) accc += wsh[t2] * base[(size_t)t2 * HH];
    feat[dcol] = accc;
  }
  for (int i = tid; i < 512; i += 256) feat[512 + i] = th[i];
  __syncthreads();

  for (int rep = 0; rep < 2; ++rep) {
    const int dcol = rep * 256 + tid;
    float a = fc1_b[dcol];
#pragma unroll 4
    for (int j = 0; j < 1024; ++j) a += feat[j] * fc1_W[(size_t)j * HH + dcol];
    hid[dcol] = fmaxf(a, 0.f);
  }
  __syncthreads();

  float p0 = 0.f, p1 = 0.f, p2 = 0.f;
  for (int dv = tid; dv < 512; dv += 256) {
    const float hv = hid[dv];
    p0 += hv * fc2_W[dv * 3 + 0];
    p1 += hv * fc2_W[dv * 3 + 1];
    p2 += hv * fc2_W[dv * 3 + 2];
  }
  feat[tid] = p0; feat[256 + tid] = p1; feat[512 + tid] = p2;
  __syncthreads();
  for (int s = 128; s > 0; s >>= 1) {
    if (tid < s) {
      feat[tid] += feat[tid + s];
      feat[256 + tid] += feat[256 + tid + s];
      feat[512 + tid] += feat[512 + tid + s];
    }
    __syncthreads();
  }
  if (tid < 3) logits[b * 3 + tid] = feat[tid * 256] + fc2_b[tid];
}

// ---------------------------------------------------------------------------
extern "C" void kernel_launch(void* const* d_in, const int* in_sizes, int n_in,
                              void* d_out, int out_size, void* d_ws, size_t ws_size,
                              hipStream_t stream) {
  const int*   text  = (const int*)d_in[0];
  const int*   topic = (const int*)d_in[1];
  const float* emb   = (const float*)d_in[2];
  const float* tWz   = (const float*)d_in[3];
  const float* tbz   = (const float*)d_in[4];
  const float* tWo   = (const float*)d_in[5];
  const float* tbo   = (const float*)d_in[6];
  const float* pWz   = (const float*)d_in[7];
  const float* pbz   = (const float*)d_in[8];
  const float* pWo   = (const float*)d_in[9];
  const float* pbo   = (const float*)d_in[10];
  const float* attW  = (const float*)d_in[11];
  const float* attb  = (const float*)d_in[12];
  const float* fc1W  = (const float*)d_in[13];
  const float* fc1b  = (const float*)d_in[14];
  const float* fc2W  = (const float*)d_in[15];
  const float* fc2b  = (const float*)d_in[16];

  float* out = (float*)d_out;            // [0,192): logits, [192,+16384): weights
  float* ws  = (float*)d_ws;

  float* text_o   = ws;                                      // 64*256*512 f32
  float* topic_hv = text_o + (size_t)NB * TTX * HH;          // 64*512 f32
  unsigned short* hring = (unsigned short*)(topic_hv + (size_t)NB * HH); // 4*64*512 bf16
  unsigned short* wxf   = hring + 131072;                    // 655360 bf16

  sd_prep<<<dim3(2560), dim3(256), 0, stream>>>(tWz, tWo, pWz, pWo,
                                                wxf, (unsigned*)hring);
  sd_recur<<<dim3(256), dim3(512), 0, stream>>>(
      text, topic, emb, tWz, tWo, pWz, pWo, tbz, tbo, pbz, pbo,
      wxf, text_o, hring, topic_hv);
  sd_att_fc<<<dim3(64), dim3(256), 0, stream>>>(text_o, topic_hv, attW, attb,
                                                fc1W, fc1b, fc2W, fc2b, out, out + 192);
}

// Round 14
// 639.786 us; speedup vs baseline: 1.2689x; 1.2689x over previous
//
#include <hip/hip_runtime.h>
#include <math.h>

#define NB 64      // batch
#define TTX 256    // text timesteps
#define TTP 16     // topic timesteps
#define EE 300     // embedding dim
#define HH 512     // hidden
#define SENT16 0x7FC1u        // bf16 NaN-payload sentinel (real h never NaN)
#define SENT32 0x7FC17FC1u

typedef __attribute__((ext_vector_type(4))) float f32x4;
typedef __attribute__((ext_vector_type(8))) short short8;

__device__ __forceinline__ unsigned short bf16cvt(float f) {
  unsigned u = __float_as_uint(f);
  u += 0x7FFFu + ((u >> 16) & 1u);   // RNE
  return (unsigned short)(u >> 16);
}

// ---------------------------------------------------------------------------
// prep: (a) poison the bf16 h-ring (every call: graph-replay deterministic),
// (b) build Bt in FRAGMENT order so xproj's B-loads are fully coalesced:
//     Bt[((tile*10 + kc)*64 + lane)*8 + e] = W[k][c]  (bf16, 0-pad k>=300)
//     with k = kc*32 + 8*(lane>>4) + e, c = tile*16 + (lane&15);
//     text weights in [0, 327680), topic in [327680, 655360).
// ---------------------------------------------------------------------------
__global__ __launch_bounds__(256) void sd_prep(
    const float* __restrict__ tWz, const float* __restrict__ tWo,
    const float* __restrict__ pWz, const float* __restrict__ pWo,
    unsigned short* __restrict__ Bt, unsigned* __restrict__ ring32)
{
  const int i = blockIdx.x * 256 + threadIdx.x;   // [0, 655360)
  if (i < 4 * NB * HH / 2) ring32[i] = SENT32;    // 65536 u32 = whole ring
  const int half = 327680;
  const int j = (i < half) ? i : i - half;
  const int e    = j & 7;
  const int lane = (j >> 3) & 63;
  const int kc   = (j >> 9) % 10;
  const int tile = (j >> 9) / 10;
  const int k = kc * 32 + 8 * (lane >> 4) + e;
  const int c = tile * 16 + (lane & 15);
  const float* W = (i < half) ? ((c < 512) ? tWz : tWo)
                              : ((c < 512) ? pWz : pWo);
  const float v = (k < 300) ? W[(size_t)k * HH + (c & 511)] : 0.f;
  Bt[i] = bf16cvt(v);
}

// ---------------------------------------------------------------------------
// xproj via MFMA bf16 (r7-verified math; B-loads fragment-coalesced:
// each short8 load is lane-contiguous 1KB per wave instead of 64-line scatter)
// ---------------------------------------------------------------------------
__global__ __launch_bounds__(256) void sd_xproj_mfma(
    const int* __restrict__ text_idx, const int* __restrict__ topic_idx,
    const float* __restrict__ emb,
    const unsigned short* __restrict__ bt_text, const unsigned short* __restrict__ bt_topic,
    const float* __restrict__ tbz, const float* __restrict__ tbo,
    const float* __restrict__ pbz, const float* __restrict__ pbo,
    float* __restrict__ xp_text, float* __restrict__ xp_topic)
{
  __shared__ alignas(16) unsigned short Als[64 * 328];
  __shared__ int tok[64];

  const bool is_text = blockIdx.x < TTX;
  const int t   = is_text ? blockIdx.x : blockIdx.x - TTX;
  const int T   = is_text ? TTX : TTP;
  const int* idx = is_text ? text_idx : topic_idx;
  const unsigned short* Bt = is_text ? bt_text : bt_topic;
  const float* bz = is_text ? tbz : pbz;
  const float* bo = is_text ? tbo : pbo;
  float* xp = is_text ? xp_text : xp_topic;

  const int tid = threadIdx.x;
  const int c0  = blockIdx.y * 256;

  if (tid < 64) tok[tid] = idx[tid * T + t];
  __syncthreads();

  {
    const int m  = tid >> 2;
    const int qt = tid & 3;
    const float* er = emb + (size_t)tok[m] * EE;
    unsigned short* ar = Als + m * 328;
    for (int j = qt; j < 75; j += 4) {
      const float4 v = *(const float4*)(er + 4 * j);
      ushort4 o;
      o.x = bf16cvt(v.x); o.y = bf16cvt(v.y);
      o.z = bf16cvt(v.z); o.w = bf16cvt(v.w);
      *(ushort4*)(ar + 4 * j) = o;
    }
    if (qt == 0) {
      for (int k = 300; k < 328; ++k) ar[k] = 0;
    }
  }
  __syncthreads();

  const int w  = tid >> 6;
  const int l  = tid & 63;
  const int lr = l & 15;
  const int lg = l >> 4;
  const int tile0 = blockIdx.y * 16 + w * 4;   // this wave's first col-tile

  f32x4 acc[4][4];
#pragma unroll
  for (int ms = 0; ms < 4; ++ms)
#pragma unroll
    for (int ns = 0; ns < 4; ++ns)
      acc[ms][ns] = (f32x4){0.f, 0.f, 0.f, 0.f};

#pragma unroll 2
  for (int kc = 0; kc < 10; ++kc) {
    short8 bfr[4];
#pragma unroll
    for (int ns = 0; ns < 4; ++ns)
      bfr[ns] = *reinterpret_cast<const short8*>(
          Bt + (((size_t)(tile0 + ns) * 10 + kc) * 64 + l) * 8);
    short8 afr[4];
#pragma unroll
    for (int ms = 0; ms < 4; ++ms)
      afr[ms] = *reinterpret_cast<const short8*>(Als + (ms * 16 + lr) * 328 + kc * 32 + 8 * lg);
#pragma unroll
    for (int ms = 0; ms < 4; ++ms)
#pragma unroll
      for (int ns = 0; ns < 4; ++ns)
        acc[ms][ns] = __builtin_amdgcn_mfma_f32_16x16x32_bf16(afr[ms], bfr[ns], acc[ms][ns], 0, 0, 0);
  }

#pragma unroll
  for (int ns = 0; ns < 4; ++ns) {
    const int cg = c0 + w * 64 + ns * 16 + lr;
    const float bias = (cg < 512) ? bz[cg] : bo[cg - 512];
#pragma unroll
    for (int ms = 0; ms < 4; ++ms) {
#pragma unroll
      for (int r = 0; r < 4; ++r) {
        const int row = ms * 16 + lg * 4 + r;
        xp[((size_t)t * 64 + row) * 1024 + cg] = acc[ms][ns][r] + bias;
      }
    }
  }
}

// ---------------------------------------------------------------------------
// Persistent recurrence kernel — r8/r9 skeleton (512 thr = 8 waves, block-
// wide sentinel poll, 2 syncs/step, vmcnt(1)) with a bf16 ring payload:
//   * ring slot = [4 rows][512 dims] bf16 (4KB); poll = ONE u64/thread;
//     staged directly into h_bf (no fp32 h_s, no convert in the poll).
//   * writers keep hprev in a REGISTER (their own previous fp32 output) —
//     bit-identical to the old h_s fp32 path.
//   * ring stores: lane pairs pack 2 bf16 into a u32 via shfl_down; even
//     threads store (one sc1 dword per pair). Poison likewise u32.
//   Protocol/proofs unchanged from r4/r9 (recycle-after-poll-success;
//   vmcnt(1) leaves only this step's own poison in flight — per-wave
//   counter, one poison instr per wave).
// ---------------------------------------------------------------------------
__global__ __launch_bounds__(512) void sd_recur(
    const float* __restrict__ tWz, const float* __restrict__ tWo,
    const float* __restrict__ pWz, const float* __restrict__ pWo,
    const float* __restrict__ xp_text, const float* __restrict__ xp_topic,
    float* __restrict__ text_out, unsigned short* __restrict__ hring,
    float* __restrict__ topic_h)
{
  __shared__ alignas(16) unsigned short h_bf[2][2080];  // bf16 h, [4 rows][520]
  __shared__ alignas(16) float red[2][2048];            // [8 wv][4 row][64 col]

  const int tid = threadIdx.x;
  const int bid = blockIdx.x;
  const int x = bid & 7;           // XCD (heuristic placement)
  const int q = bid >> 3;
  const int g = x + 8 * (q >> 4);  // batch group 0..15
  const int slice = q & 15;        // dim slice 0..15
  const int b0 = g * 4;
  const int c_base = slice * 32;

  const int wv = tid >> 6;         // wave id = k-eighth (0..7)
  const int lane = tid & 63;
  const int lg = lane >> 4;        // k-slot group 0..3
  const int l15 = lane & 15;

  const int bi_w = tid >> 5;       // writer mapping (tid<128): batch row 0..3
  const int dw = tid & 31;

  // writer thread's ring offset within a slot (bf16 units)
  const size_t wslot_off = (size_t)(b0 + bi_w) * HH + c_base + dw;

  int u = 0;  // global step counter across both phases

  for (int ph = 0; ph < 2; ++ph) {
    const float* Wz = ph ? pWz : tWz;
    const float* Wo = ph ? pWo : tWo;
    const float* xp = ph ? xp_topic : xp_text;
    const int T = ph ? TTP : TTX;

    float hprev_r = 0.f;  // writer's own h (fp32-exact), reset per phase

    // --- prep W h-part bf16 B-fragments (once per phase) ----------------
    short8 wfrag[4][2];
#pragma unroll
    for (int ns = 0; ns < 4; ++ns) {
      const float* Wg = (ns < 2) ? Wz : Wo;
      const int dim = (ns & 1) * 16 + l15;
#pragma unroll
      for (int kc = 0; kc < 2; ++kc) {
        const int kb = wv * 64 + kc * 32 + 8 * lg;
        short8 f;
#pragma unroll
        for (int e = 0; e < 8; ++e)
          f[e] = (short)bf16cvt(Wg[(size_t)(EE + kb + e) * HH + c_base + dim]);
        wfrag[ns][kc] = f;
      }
    }

    for (int t = 0; t < T; ++t, ++u) {
      const int cur = u & 1;
      const bool do_poll = (u > 0);
      const bool use_h   = (t > 0);

      float xpz = 0.f, xpo = 0.f;
      if (tid < 128) {
        const float* xpr = xp + ((size_t)t * 64 + (b0 + bi_w)) * 1024 + c_base + dw;
        xpz = xpr[0];
        xpo = xpr[512];
      }

      if (do_poll) {
        // block-wide poll-stage: one u64 (4 bf16) per thread
        const unsigned long long* src64 = (const unsigned long long*)
            (hring + (size_t)(u & 3) * NB * HH + (size_t)b0 * HH);
        unsigned long long v;
        for (;;) {
          v = __hip_atomic_load(src64 + tid, __ATOMIC_RELAXED, __HIP_MEMORY_SCOPE_AGENT);
          const unsigned lo = (unsigned)v, hi = (unsigned)(v >> 32);
          if ((lo & 0xFFFFu) != SENT16 && (lo >> 16) != SENT16 &&
              (hi & 0xFFFFu) != SENT16 && (hi >> 16) != SENT16) break;
          __builtin_amdgcn_s_sleep(1);
        }
        *(unsigned long long*)&h_bf[cur][(tid >> 7) * 520 + (tid & 127) * 4] = v;
      }

      __syncthreads();  // whole block's poll complete + stage visible

      // Safe to recycle slot (u-1)&3 now (poll success => consumers done).
      if (do_poll && tid < 128 && !(tid & 1))
        __hip_atomic_store((unsigned*)(hring + (size_t)((u - 1) & 3) * NB * HH + wslot_off),
                           SENT32, __ATOMIC_RELAXED, __HIP_MEMORY_SCOPE_AGENT);

      if (use_h) {
        const unsigned short* hb = &h_bf[cur][(lane & 3) * 520 + wv * 64 + 8 * lg];
        const short8 a0 = *reinterpret_cast<const short8*>(hb + 0);
        const short8 a1 = *reinterpret_cast<const short8*>(hb + 32);

        f32x4 acc[4];
#pragma unroll
        for (int ns = 0; ns < 4; ++ns) {
          acc[ns] = (f32x4){0.f, 0.f, 0.f, 0.f};
          acc[ns] = __builtin_amdgcn_mfma_f32_16x16x32_bf16(a0, wfrag[ns][0], acc[ns], 0, 0, 0);
          acc[ns] = __builtin_amdgcn_mfma_f32_16x16x32_bf16(a1, wfrag[ns][1], acc[ns], 0, 0, 0);
        }
        if (lane < 16) {
#pragma unroll
          for (int ns = 0; ns < 4; ++ns)
#pragma unroll
            for (int r = 0; r < 4; ++r)
              red[cur][wv * 256 + r * 64 + ns * 16 + lane] = acc[ns][r];
        }
      }

      __syncthreads();  // partials visible

      if (tid < 128) {
        float zp = 0.f, op = 0.f;
        if (use_h) {
#pragma unroll
          for (int k2 = 0; k2 < 8; ++k2) {
            zp += red[cur][k2 * 256 + bi_w * 64 + dw];        // gate z
            op += red[cur][k2 * 256 + bi_w * 64 + 32 + dw];   // gate o
          }
        }
        const float a = zp + xpz;
        const float z = 1.f / (1.f + __expf(-a));
        const float bv = op + xpo;
        const float ab = fabsf(bv);
        const float e2 = __expf(-2.f * ab);
        const float htl = __builtin_copysignf((1.f - e2) / (1.f + e2), bv);
        const float hn = (1.f - z) * hprev_r + z * htl;
        hprev_r = hn;

        // pack 2 bf16 per lane pair; even thread stores one sc1 dword
        const unsigned short hb16 = bf16cvt(hn);
        const unsigned packed = (unsigned)hb16 |
                                ((unsigned)__shfl_down((int)hb16, 1, 64) << 16);

        // drain everything EXCEPT this step's own poison (per-wave counter,
        // one poison instr) — orders the step-(u-2) same-address poison
        asm volatile("s_waitcnt vmcnt(1)" ::: "memory");
        if (!(tid & 1))
          __hip_atomic_store((unsigned*)(hring + (size_t)((u + 1) & 3) * NB * HH + wslot_off),
                             packed, __ATOMIC_RELAXED, __HIP_MEMORY_SCOPE_AGENT);
        if (ph == 0)
          text_out[((size_t)(b0 + bi_w) * TTX + t) * HH + c_base + dw] = hn;
        else if (t == T - 1)
          topic_h[(size_t)(b0 + bi_w) * HH + c_base + dw] = hn;
      }
      // no trailing barrier: 2-deep buffers tolerate one-phase skew
    }
  }
}

// ---------------------------------------------------------------------------
// attention + FC head fused (unchanged from round 9/10, verified)
// ---------------------------------------------------------------------------
__global__ __launch_bounds__(256) void sd_att_fc(
    const float* __restrict__ text_out, const float* __restrict__ topic_h,
    const float* __restrict__ att_W, const float* __restrict__ att_b,
    const float* __restrict__ fc1_W, const float* __restrict__ fc1_b,
    const float* __restrict__ fc2_W, const float* __restrict__ fc2_b,
    float* __restrict__ logits, float* __restrict__ weights_out)
{
  __shared__ alignas(16) float aw[1024];
  __shared__ alignas(16) float th[512];
  __shared__ float sc_s[256];
  __shared__ float sred[256];
  __shared__ float wsh[256];
  __shared__ alignas(16) float feat[1024];
  __shared__ float hid[512];
  const int b = blockIdx.x, tid = threadIdx.x;

  for (int i = tid; i < 1024; i += 256) aw[i] = att_W[i];
  for (int i = tid; i < 512; i += 256) th[i] = topic_h[(size_t)b * HH + i];
  __syncthreads();

  float part = 0.f;
  for (int i = tid; i < 512; i += 256) part += th[i] * aw[512 + i];
  sred[tid] = part;
  __syncthreads();
  for (int s = 128; s > 0; s >>= 1) { if (tid < s) sred[tid] += sred[tid + s]; __syncthreads(); }
  const float cb = sred[0] + att_b[0];
  __syncthreads();

  const int gr = tid >> 5, ln = tid & 31;
  for (int rep = 0; rep < 32; ++rep) {
    const int t = rep * 8 + gr;
    const float* row = text_out + ((size_t)b * TTX + t) * HH;
    float p = 0.f;
#pragma unroll
    for (int j = 0; j < 4; ++j) {
      const float4 v  = *(const float4*)(row + ln * 4 + 128 * j);
      const float4 w4 = *(const float4*)(aw  + ln * 4 + 128 * j);
      p += v.x * w4.x + v.y * w4.y + v.z * w4.z + v.w * w4.w;
    }
#pragma unroll
    for (int o = 16; o > 0; o >>= 1) p += __shfl_xor(p, o, 32);
    if (ln == 0) sc_s[t] = p + cb;
  }
  __syncthreads();

  const float sc = sc_s[tid];
  sred[tid] = sc; __syncthreads();
  for (int s = 128; s > 0; s >>= 1) { if (tid < s) sred[tid] = fmaxf(sred[tid], sred[tid + s]); __syncthreads(); }
  const float m = sred[0];
  __syncthreads();
  const float e = expf(sc - m);
  sred[tid] = e; __syncthreads();
  for (int s = 128; s > 0; s >>= 1) { if (tid < s) sred[tid] += sred[tid + s]; __syncthreads(); }
  const float wv = e / sred[0];
  wsh[tid] = wv;
  weights_out[(size_t)b * TTX + tid] = wv;
  __syncthreads();

  for (int rep = 0; rep < 2; ++rep) {
    const int dcol = rep * 256 + tid;
    float accc = 0.f;
    const float* base = text_out + (size_t)b * TTX * HH + dcol;
    for (int t2 = 0; t2 < TTX; ++t2) accc += wsh[t2] * base[(size_t)t2 * HH];
    feat[dcol] = accc;
  }
  for (int i = tid; i < 512; i += 256) feat[512 + i] = th[i];
  __syncthreads();

  for (int rep = 0; rep < 2; ++rep) {
    const int dcol = rep * 256 + tid;
    float a = fc1_b[dcol];
#pragma unroll 4
    for (int j = 0; j < 1024; ++j) a += feat[j] * fc1_W[(size_t)j * HH + dcol];
    hid[dcol] = fmaxf(a, 0.f);
  }
  __syncthreads();

  float p0 = 0.f, p1 = 0.f, p2 = 0.f;
  for (int dv = tid; dv < 512; dv += 256) {
    const float hv = hid[dv];
    p0 += hv * fc2_W[dv * 3 + 0];
    p1 += hv * fc2_W[dv * 3 + 1];
    p2 += hv * fc2_W[dv * 3 + 2];
  }
  feat[tid] = p0; feat[256 + tid] = p1; feat[512 + tid] = p2;
  __syncthreads();
  for (int s = 128; s > 0; s >>= 1) {
    if (tid < s) {
      feat[tid] += feat[tid + s];
      feat[256 + tid] += feat[256 + tid + s];
      feat[512 + tid] += feat[512 + tid + s];
    }
    __syncthreads();
  }
  if (tid < 3) logits[b * 3 + tid] = feat[tid * 256] + fc2_b[tid];
}

// ---------------------------------------------------------------------------
extern "C" void kernel_launch(void* const* d_in, const int* in_sizes, int n_in,
                              void* d_out, int out_size, void* d_ws, size_t ws_size,
                              hipStream_t stream) {
  const int*   text  = (const int*)d_in[0];
  const int*   topic = (const int*)d_in[1];
  const float* emb   = (const float*)d_in[2];
  const float* tWz   = (const float*)d_in[3];
  const float* tbz   = (const float*)d_in[4];
  const float* tWo   = (const float*)d_in[5];
  const float* tbo   = (const float*)d_in[6];
  const float* pWz   = (const float*)d_in[7];
  const float* pbz   = (const float*)d_in[8];
  const float* pWo   = (const float*)d_in[9];
  const float* pbo   = (const float*)d_in[10];
  const float* attW  = (const float*)d_in[11];
  const float* attb  = (const float*)d_in[12];
  const float* fc1W  = (const float*)d_in[13];
  const float* fc1b  = (const float*)d_in[14];
  const float* fc2W  = (const float*)d_in[15];
  const float* fc2b  = (const float*)d_in[16];

  float* out = (float*)d_out;            // [0,192): logits, [192,+16384): weights
  float* ws  = (float*)d_ws;

  float* xp_text  = ws;                                    // 256*64*1024
  float* xp_topic = xp_text + (size_t)TTX * 64 * 1024;     // 16*64*1024
  float* text_o   = xp_topic + (size_t)TTP * 64 * 1024;    // 64*256*512
  float* topic_hv = text_o + (size_t)NB * TTX * HH;        // 64*512
  unsigned short* hring = (unsigned short*)(topic_hv + (size_t)NB * HH); // 4*64*512 bf16

  // bf16 fragment-order Bt buffers live in the text_o region (text|topic):
  // prep+xproj finish before sd_recur writes text_o (stream-serial) => safe.
  unsigned short* bt_text  = (unsigned short*)text_o;      // 327680 bf16
  unsigned short* bt_topic = bt_text + 327680;             // 327680 bf16

  sd_prep<<<dim3(2560), dim3(256), 0, stream>>>(tWz, tWo, pWz, pWo,
                                                bt_text, (unsigned*)hring);
  sd_xproj_mfma<<<dim3(TTX + TTP, 4), dim3(256), 0, stream>>>(
      text, topic, emb, bt_text, bt_topic, tbz, tbo, pbz, pbo, xp_text, xp_topic);
  sd_recur<<<dim3(256), dim3(512), 0, stream>>>(tWz, tWo, pWz, pWo, xp_text, xp_topic,
                                                text_o, hring, topic_hv);
  sd_att_fc<<<dim3(64), dim3(256), 0, stream>>>(text_o, topic_hv, attW, attb,
                                                fc1W, fc1b, fc2W, fc2b, out, out + 192);
}

// Round 15
// 515.629 us; speedup vs baseline: 1.5744x; 1.2408x over previous
//
#include <hip/hip_runtime.h>
#include <math.h>

#define NB 64      // batch
#define TTX 256    // text timesteps
#define TTP 16     // topic timesteps
#define EE 300     // embedding dim
#define HH 512     // hidden
#define SENT16 0x7FC1u        // bf16 NaN-payload sentinel (real h never NaN)
#define SENT32 0x7FC17FC1u

typedef __attribute__((ext_vector_type(4))) float f32x4;
typedef __attribute__((ext_vector_type(8))) short short8;

__device__ __forceinline__ unsigned short bf16cvt(float f) {
  unsigned u = __float_as_uint(f);
  u += 0x7FFFu + ((u >> 16) & 1u);   // RNE
  return (unsigned short)(u >> 16);
}

// ---------------------------------------------------------------------------
// prep: (a) poison the bf16 h-ring (every call: graph-replay deterministic),
// (b) build Bt in FRAGMENT order (r10-verified, unchanged)
// ---------------------------------------------------------------------------
__global__ __launch_bounds__(256) void sd_prep(
    const float* __restrict__ tWz, const float* __restrict__ tWo,
    const float* __restrict__ pWz, const float* __restrict__ pWo,
    unsigned short* __restrict__ Bt, unsigned* __restrict__ ring32)
{
  const int i = blockIdx.x * 256 + threadIdx.x;   // [0, 655360)
  if (i < 4 * NB * HH / 2) ring32[i] = SENT32;    // 65536 u32 = whole ring
  const int half = 327680;
  const int j = (i < half) ? i : i - half;
  const int e    = j & 7;
  const int lane = (j >> 3) & 63;
  const int kc   = (j >> 9) % 10;
  const int tile = (j >> 9) / 10;
  const int k = kc * 32 + 8 * (lane >> 4) + e;
  const int c = tile * 16 + (lane & 15);
  const float* W = (i < half) ? ((c < 512) ? tWz : tWo)
                              : ((c < 512) ? pWz : pWo);
  const float v = (k < 300) ? W[(size_t)k * HH + (c & 511)] : 0.f;
  Bt[i] = bf16cvt(v);
}

// ---------------------------------------------------------------------------
// xproj via MFMA bf16 (r10-verified, unchanged)
// ---------------------------------------------------------------------------
__global__ __launch_bounds__(256) void sd_xproj_mfma(
    const int* __restrict__ text_idx, const int* __restrict__ topic_idx,
    const float* __restrict__ emb,
    const unsigned short* __restrict__ bt_text, const unsigned short* __restrict__ bt_topic,
    const float* __restrict__ tbz, const float* __restrict__ tbo,
    const float* __restrict__ pbz, const float* __restrict__ pbo,
    float* __restrict__ xp_text, float* __restrict__ xp_topic)
{
  __shared__ alignas(16) unsigned short Als[64 * 328];
  __shared__ int tok[64];

  const bool is_text = blockIdx.x < TTX;
  const int t   = is_text ? blockIdx.x : blockIdx.x - TTX;
  const int T   = is_text ? TTX : TTP;
  const int* idx = is_text ? text_idx : topic_idx;
  const unsigned short* Bt = is_text ? bt_text : bt_topic;
  const float* bz = is_text ? tbz : pbz;
  const float* bo = is_text ? tbo : pbo;
  float* xp = is_text ? xp_text : xp_topic;

  const int tid = threadIdx.x;
  const int c0  = blockIdx.y * 256;

  if (tid < 64) tok[tid] = idx[tid * T + t];
  __syncthreads();

  {
    const int m  = tid >> 2;
    const int qt = tid & 3;
    const float* er = emb + (size_t)tok[m] * EE;
    unsigned short* ar = Als + m * 328;
    for (int j = qt; j < 75; j += 4) {
      const float4 v = *(const float4*)(er + 4 * j);
      ushort4 o;
      o.x = bf16cvt(v.x); o.y = bf16cvt(v.y);
      o.z = bf16cvt(v.z); o.w = bf16cvt(v.w);
      *(ushort4*)(ar + 4 * j) = o;
    }
    if (qt == 0) {
      for (int k = 300; k < 328; ++k) ar[k] = 0;
    }
  }
  __syncthreads();

  const int w  = tid >> 6;
  const int l  = tid & 63;
  const int lr = l & 15;
  const int lg = l >> 4;
  const int tile0 = blockIdx.y * 16 + w * 4;   // this wave's first col-tile

  f32x4 acc[4][4];
#pragma unroll
  for (int ms = 0; ms < 4; ++ms)
#pragma unroll
    for (int ns = 0; ns < 4; ++ns)
      acc[ms][ns] = (f32x4){0.f, 0.f, 0.f, 0.f};

#pragma unroll 2
  for (int kc = 0; kc < 10; ++kc) {
    short8 bfr[4];
#pragma unroll
    for (int ns = 0; ns < 4; ++ns)
      bfr[ns] = *reinterpret_cast<const short8*>(
          Bt + (((size_t)(tile0 + ns) * 10 + kc) * 64 + l) * 8);
    short8 afr[4];
#pragma unroll
    for (int ms = 0; ms < 4; ++ms)
      afr[ms] = *reinterpret_cast<const short8*>(Als + (ms * 16 + lr) * 328 + kc * 32 + 8 * lg);
#pragma unroll
    for (int ms = 0; ms < 4; ++ms)
#pragma unroll
      for (int ns = 0; ns < 4; ++ns)
        acc[ms][ns] = __builtin_amdgcn_mfma_f32_16x16x32_bf16(afr[ms], bfr[ns], acc[ms][ns], 0, 0, 0);
  }

#pragma unroll
  for (int ns = 0; ns < 4; ++ns) {
    const int cg = c0 + w * 64 + ns * 16 + lr;
    const float bias = (cg < 512) ? bz[cg] : bo[cg - 512];
#pragma unroll
    for (int ms = 0; ms < 4; ++ms) {
#pragma unroll
      for (int r = 0; r < 4; ++r) {
        const int row = ms * 16 + lg * 4 + r;
        xp[((size_t)t * 64 + row) * 1024 + cg] = acc[ms][ns][r] + bias;
      }
    }
  }
}

// ---------------------------------------------------------------------------
// Persistent recurrence kernel — r10/r14-verified, byte-identical.
// ---------------------------------------------------------------------------
__global__ __launch_bounds__(512) void sd_recur(
    const float* __restrict__ tWz, const float* __restrict__ tWo,
    const float* __restrict__ pWz, const float* __restrict__ pWo,
    const float* __restrict__ xp_text, const float* __restrict__ xp_topic,
    float* __restrict__ text_out, unsigned short* __restrict__ hring,
    float* __restrict__ topic_h)
{
  __shared__ alignas(16) unsigned short h_bf[2][2080];  // bf16 h, [4 rows][520]
  __shared__ alignas(16) float red[2][2048];            // [8 wv][4 row][64 col]

  const int tid = threadIdx.x;
  const int bid = blockIdx.x;
  const int x = bid & 7;           // XCD (heuristic placement)
  const int q = bid >> 3;
  const int g = x + 8 * (q >> 4);  // batch group 0..15
  const int slice = q & 15;        // dim slice 0..15
  const int b0 = g * 4;
  const int c_base = slice * 32;

  const int wv = tid >> 6;         // wave id = k-eighth (0..7)
  const int lane = tid & 63;
  const int lg = lane >> 4;        // k-slot group 0..3
  const int l15 = lane & 15;

  const int bi_w = tid >> 5;       // writer mapping (tid<128): batch row 0..3
  const int dw = tid & 31;

  // writer thread's ring offset within a slot (bf16 units)
  const size_t wslot_off = (size_t)(b0 + bi_w) * HH + c_base + dw;

  int u = 0;  // global step counter across both phases

  for (int ph = 0; ph < 2; ++ph) {
    const float* Wz = ph ? pWz : tWz;
    const float* Wo = ph ? pWo : tWo;
    const float* xp = ph ? xp_topic : xp_text;
    const int T = ph ? TTP : TTX;

    float hprev_r = 0.f;  // writer's own h (fp32-exact), reset per phase

    // --- prep W h-part bf16 B-fragments (once per phase) ----------------
    short8 wfrag[4][2];
#pragma unroll
    for (int ns = 0; ns < 4; ++ns) {
      const float* Wg = (ns < 2) ? Wz : Wo;
      const int dim = (ns & 1) * 16 + l15;
#pragma unroll
      for (int kc = 0; kc < 2; ++kc) {
        const int kb = wv * 64 + kc * 32 + 8 * lg;
        short8 f;
#pragma unroll
        for (int e = 0; e < 8; ++e)
          f[e] = (short)bf16cvt(Wg[(size_t)(EE + kb + e) * HH + c_base + dim]);
        wfrag[ns][kc] = f;
      }
    }

    for (int t = 0; t < T; ++t, ++u) {
      const int cur = u & 1;
      const bool do_poll = (u > 0);
      const bool use_h   = (t > 0);

      float xpz = 0.f, xpo = 0.f;
      if (tid < 128) {
        const float* xpr = xp + ((size_t)t * 64 + (b0 + bi_w)) * 1024 + c_base + dw;
        xpz = xpr[0];
        xpo = xpr[512];
      }

      if (do_poll) {
        // block-wide poll-stage: one u64 (4 bf16) per thread
        const unsigned long long* src64 = (const unsigned long long*)
            (hring + (size_t)(u & 3) * NB * HH + (size_t)b0 * HH);
        unsigned long long v;
        for (;;) {
          v = __hip_atomic_load(src64 + tid, __ATOMIC_RELAXED, __HIP_MEMORY_SCOPE_AGENT);
          const unsigned lo = (unsigned)v, hi = (unsigned)(v >> 32);
          if ((lo & 0xFFFFu) != SENT16 && (lo >> 16) != SENT16 &&
              (hi & 0xFFFFu) != SENT16 && (hi >> 16) != SENT16) break;
          __builtin_amdgcn_s_sleep(1);
        }
        *(unsigned long long*)&h_bf[cur][(tid >> 7) * 520 + (tid & 127) * 4] = v;
      }

      __syncthreads();  // whole block's poll complete + stage visible

      // Safe to recycle slot (u-1)&3 now (poll success => consumers done).
      if (do_poll && tid < 128 && !(tid & 1))
        __hip_atomic_store((unsigned*)(hring + (size_t)((u - 1) & 3) * NB * HH + wslot_off),
                           SENT32, __ATOMIC_RELAXED, __HIP_MEMORY_SCOPE_AGENT);

      if (use_h) {
        const unsigned short* hb = &h_bf[cur][(lane & 3) * 520 + wv * 64 + 8 * lg];
        const short8 a0 = *reinterpret_cast<const short8*>(hb + 0);
        const short8 a1 = *reinterpret_cast<const short8*>(hb + 32);

        f32x4 acc[4];
#pragma unroll
        for (int ns = 0; ns < 4; ++ns) {
          acc[ns] = (f32x4){0.f, 0.f, 0.f, 0.f};
          acc[ns] = __builtin_amdgcn_mfma_f32_16x16x32_bf16(a0, wfrag[ns][0], acc[ns], 0, 0, 0);
          acc[ns] = __builtin_amdgcn_mfma_f32_16x16x32_bf16(a1, wfrag[ns][1], acc[ns], 0, 0, 0);
        }
        if (lane < 16) {
#pragma unroll
          for (int ns = 0; ns < 4; ++ns)
#pragma unroll
            for (int r = 0; r < 4; ++r)
              red[cur][wv * 256 + r * 64 + ns * 16 + lane] = acc[ns][r];
        }
      }

      __syncthreads();  // partials visible

      if (tid < 128) {
        float zp = 0.f, op = 0.f;
        if (use_h) {
#pragma unroll
          for (int k2 = 0; k2 < 8; ++k2) {
            zp += red[cur][k2 * 256 + bi_w * 64 + dw];        // gate z
            op += red[cur][k2 * 256 + bi_w * 64 + 32 + dw];   // gate o
          }
        }
        const float a = zp + xpz;
        const float z = 1.f / (1.f + __expf(-a));
        const float bv = op + xpo;
        const float ab = fabsf(bv);
        const float e2 = __expf(-2.f * ab);
        const float htl = __builtin_copysignf((1.f - e2) / (1.f + e2), bv);
        const float hn = (1.f - z) * hprev_r + z * htl;
        hprev_r = hn;

        // pack 2 bf16 per lane pair; even thread stores one sc1 dword
        const unsigned short hb16 = bf16cvt(hn);
        const unsigned packed = (unsigned)hb16 |
                                ((unsigned)__shfl_down((int)hb16, 1, 64) << 16);

        // drain everything EXCEPT this step's own poison (per-wave counter,
        // one poison instr) — orders the step-(u-2) same-address poison
        asm volatile("s_waitcnt vmcnt(1)" ::: "memory");
        if (!(tid & 1))
          __hip_atomic_store((unsigned*)(hring + (size_t)((u + 1) & 3) * NB * HH + wslot_off),
                             packed, __ATOMIC_RELAXED, __HIP_MEMORY_SCOPE_AGENT);
        if (ph == 0)
          text_out[((size_t)(b0 + bi_w) * TTX + t) * HH + c_base + dw] = hn;
        else if (t == T - 1)
          topic_h[(size_t)(b0 + bi_w) * HH + c_base + dw] = hn;
      }
      // no trailing barrier: 2-deep buffers tolerate one-phase skew
    }
  }
}

// ---------------------------------------------------------------------------
// attention + FC head fused — 1024-thread edition (was 256 = 1 wave/SIMD,
// latency-bound on its serial L2-streaming loops with 192 CUs idle).
//   * 16 waves = 4/SIMD;
//   * context and fc1 loops split in half over k/t2 across thread-halves
//     (thread = (dcol, half)) with LDS partial combine -> 2x shorter serial
//     chains on top of 4x the wave-level latency hiding.
//   Math identical up to fp32 reassociation (two-half sums).
// ---------------------------------------------------------------------------
__global__ __launch_bounds__(1024) void sd_att_fc(
    const float* __restrict__ text_out, const float* __restrict__ topic_h,
    const float* __restrict__ att_W, const float* __restrict__ att_b,
    const float* __restrict__ fc1_W, const float* __restrict__ fc1_b,
    const float* __restrict__ fc2_W, const float* __restrict__ fc2_b,
    float* __restrict__ logits, float* __restrict__ weights_out)
{
  __shared__ alignas(16) float aw[1024];
  __shared__ alignas(16) float th[512];
  __shared__ float sc_s[256];
  __shared__ float sred[1024];
  __shared__ float wsh[256];
  __shared__ alignas(16) float feat[1024];
  __shared__ float part2[1024];
  __shared__ float hid[512];
  const int b = blockIdx.x, tid = threadIdx.x;

  aw[tid] = att_W[tid];
  if (tid < 512) th[tid] = topic_h[(size_t)b * HH + tid];
  __syncthreads();

  // cb = dot(topic_h, aw[512:]) + att_b
  sred[tid] = (tid < 512) ? th[tid] * aw[512 + tid] : 0.f;
  __syncthreads();
  for (int s = 512; s > 0; s >>= 1) { if (tid < s) sred[tid] += sred[tid + s]; __syncthreads(); }
  const float cb = sred[0] + att_b[0];
  __syncthreads();

  // scores: 32 row-groups x 32 lanes, coalesced float4 reads + shfl reduce
  const int gr = tid >> 5, ln = tid & 31;
  for (int rep = 0; rep < 8; ++rep) {
    const int t = rep * 32 + gr;
    const float* row = text_out + ((size_t)b * TTX + t) * HH;
    float p = 0.f;
#pragma unroll
    for (int j = 0; j < 4; ++j) {
      const float4 v  = *(const float4*)(row + ln * 4 + 128 * j);
      const float4 w4 = *(const float4*)(aw  + ln * 4 + 128 * j);
      p += v.x * w4.x + v.y * w4.y + v.z * w4.z + v.w * w4.w;
    }
#pragma unroll
    for (int o = 16; o > 0; o >>= 1) p += __shfl_xor(p, o, 32);
    if (ln == 0) sc_s[t] = p + cb;
  }
  __syncthreads();

  // softmax over 256 scores (tid<256 active; all threads join reductions)
  const float sc = (tid < 256) ? sc_s[tid] : -3.4e38f;
  sred[tid] = sc;
  __syncthreads();
  for (int s = 512; s > 0; s >>= 1) { if (tid < s) sred[tid] = fmaxf(sred[tid], sred[tid + s]); __syncthreads(); }
  const float m = sred[0];
  __syncthreads();
  const float e = (tid < 256) ? expf(sc - m) : 0.f;
  sred[tid] = e;
  __syncthreads();
  for (int s = 512; s > 0; s >>= 1) { if (tid < s) sred[tid] += sred[tid + s]; __syncthreads(); }
  const float wv = e / sred[0];
  if (tid < 256) {
    wsh[tid] = wv;
    weights_out[(size_t)b * TTX + tid] = wv;
  }
  __syncthreads();

  // context: thread = (dcol, t2-half); combine halves in LDS
  {
    const int dcol = tid & 511, kh = tid >> 9;
    float accc = 0.f;
    const float* base = text_out + (size_t)b * TTX * HH + dcol;
    const int t0 = kh * 128;
    for (int t2 = t0; t2 < t0 + 128; ++t2) accc += wsh[t2] * base[(size_t)t2 * HH];
    part2[tid] = accc;
  }
  __syncthreads();
  if (tid < 512) {
    feat[tid] = part2[tid] + part2[tid + 512];
    feat[512 + tid] = th[tid];
  }
  __syncthreads();

  // fc1 + relu: thread = (dcol, k-half); combine halves in LDS
  {
    const int dcol = tid & 511, kh = tid >> 9;
    float a = 0.f;
    const int j0 = kh * 512;
#pragma unroll 8
    for (int j = j0; j < j0 + 512; ++j) a += feat[j] * fc1_W[(size_t)j * HH + dcol];
    part2[tid] = a;
  }
  __syncthreads();
  if (tid < 512) hid[tid] = fmaxf(part2[tid] + part2[tid + 512] + fc1_b[tid], 0.f);
  __syncthreads();

  // fc2: 512 threads, tree-reduce three logits
  float p0 = 0.f, p1 = 0.f, p2 = 0.f;
  if (tid < 512) {
    const float hv = hid[tid];
    p0 = hv * fc2_W[tid * 3 + 0];
    p1 = hv * fc2_W[tid * 3 + 1];
    p2 = hv * fc2_W[tid * 3 + 2];
  }
  sred[tid] = p0; part2[tid] = p1; feat[tid] = p2;
  __syncthreads();
  for (int s = 512; s > 0; s >>= 1) {
    if (tid < s) {
      sred[tid]  += sred[tid + s];
      part2[tid] += part2[tid + s];
      feat[tid]  += feat[tid + s];
    }
    __syncthreads();
  }
  if (tid == 0) {
    logits[b * 3 + 0] = sred[0]  + fc2_b[0];
    logits[b * 3 + 1] = part2[0] + fc2_b[1];
    logits[b * 3 + 2] = feat[0]  + fc2_b[2];
  }
}

// ---------------------------------------------------------------------------
extern "C" void kernel_launch(void* const* d_in, const int* in_sizes, int n_in,
                              void* d_out, int out_size, void* d_ws, size_t ws_size,
                              hipStream_t stream) {
  const int*   text  = (const int*)d_in[0];
  const int*   topic = (const int*)d_in[1];
  const float* emb   = (const float*)d_in[2];
  const float* tWz   = (const float*)d_in[3];
  const float* tbz   = (const float*)d_in[4];
  const float* tWo   = (const float*)d_in[5];
  const float* tbo   = (const float*)d_in[6];
  const float* pWz   = (const float*)d_in[7];
  const float* pbz   = (const float*)d_in[8];
  const float* pWo   = (const float*)d_in[9];
  const float* pbo   = (const float*)d_in[10];
  const float* attW  = (const float*)d_in[11];
  const float* attb  = (const float*)d_in[12];
  const float* fc1W  = (const float*)d_in[13];
  const float* fc1b  = (const float*)d_in[14];
  const float* fc2W  = (const float*)d_in[15];
  const float* fc2b  = (const float*)d_in[16];

  float* out = (float*)d_out;            // [0,192): logits, [192,+16384): weights
  float* ws  = (float*)d_ws;

  float* xp_text  = ws;                                    // 256*64*1024
  float* xp_topic = xp_text + (size_t)TTX * 64 * 1024;     // 16*64*1024
  float* text_o   = xp_topic + (size_t)TTP * 64 * 1024;    // 64*256*512
  float* topic_hv = text_o + (size_t)NB * TTX * HH;        // 64*512
  unsigned short* hring = (unsigned short*)(topic_hv + (size_t)NB * HH); // 4*64*512 bf16

  // bf16 fragment-order Bt buffers live in the text_o region (text|topic):
  // prep+xproj finish before sd_recur writes text_o (stream-serial) => safe.
  unsigned short* bt_text  = (unsigned short*)text_o;      // 327680 bf16
  unsigned short* bt_topic = bt_text + 327680;             // 327680 bf16

  sd_prep<<<dim3(2560), dim3(256), 0, stream>>>(tWz, tWo, pWz, pWo,
                                                bt_text, (unsigned*)hring);
  sd_xproj_mfma<<<dim3(TTX + TTP, 4), dim3(256), 0, stream>>>(
      text, topic, emb, bt_text, bt_topic, tbz, tbo, pbz, pbo, xp_text, xp_topic);
  sd_recur<<<dim3(256), dim3(512), 0, stream>>>(tWz, tWo, pWz, pWo, xp_text, xp_topic,
                                                text_o, hring, topic_hv);
  sd_att_fc<<<dim3(64), dim3(1024), 0, stream>>>(text_o, topic_hv, attW, attb,
                                                 fc1W, fc1b, fc2W, fc2b, out, out + 192);
}